// Round 2
// baseline (1855.099 us; speedup 1.0000x reference)
//
#include <hip/hip_runtime.h>
#include <hip/hip_bf16.h>
#include <math.h>

#define LNUM 12
#define BNUM 8
#define DNUM 2048
#define VNUM 32000
#define HNUM 64
#define HDNUM 64
#define GNUM 8
#define NNUM 128
#define KNUM 4
#define INUM (HNUM*HDNUM)              /* 4096 */
#define CONVNUM (INUM + 2*GNUM*NNUM)   /* 6144 */
#define PNUM (INUM + CONVNUM + HNUM)   /* 14304 */

#define IP_KC 8                        /* split-K chunks for in_proj (256 rows each) */
#define OP_KC 64                       /* split-K chunks for out_proj (64 rows each) */

__device__ __forceinline__ float sigmoidf_(float x){ return 1.f/(1.f+expf(-x)); }

// ---------------- embedding gather + sumsq partials ----------------
__global__ void k_embed(const int* __restrict__ ids, const float* __restrict__ emb,
                        float* __restrict__ h, float* __restrict__ sqp){
  int b = blockIdx.x; int t = threadIdx.x;
  const float* src = emb + (size_t)ids[b]*DNUM;
  float* dst = h + (size_t)b*DNUM;
  for (int d = t*4; d < DNUM; d += 256*4)
    *(float4*)(dst + d) = *(const float4*)(src + d);
  __shared__ float red[4];
  for (int j = 0; j < 8; ++j){
    float v = src[j*256 + t];
    float q = v*v;
    q += __shfl_xor(q,32); q += __shfl_xor(q,16); q += __shfl_xor(q,8);
    q += __shfl_xor(q,4);  q += __shfl_xor(q,2);  q += __shfl_xor(q,1);
    if ((t & 63) == 0) red[t>>6] = q;
    __syncthreads();
    if (t == 0) sqp[b*8 + j] = red[0]+red[1]+red[2]+red[3];
    __syncthreads();
  }
}

// ---------------- in_proj GEMV (rmsnorm fused via sq_part) ----------------
__global__ __launch_bounds__(64) void k_inproj(const float* __restrict__ h,
                                               const float* __restrict__ sqp,
                                               const float* __restrict__ nw,
                                               const float* __restrict__ W,
                                               float* __restrict__ part1){
  int t = threadIdx.x;
  int pb = blockIdx.x;   // 0..55: 256 p-cols
  int kc = blockIdx.y;   // 0..7 : 256 d-rows
  __shared__ float xs[BNUM][256];
  __shared__ float invs[BNUM];
  {
    int b = t>>3, j = t&7;
    float v = sqp[b*8 + j];
    v += __shfl_xor(v,1); v += __shfl_xor(v,2); v += __shfl_xor(v,4);
    if (j == 0) invs[b] = rsqrtf(v*(1.f/DNUM) + 1e-5f);
  }
  __syncthreads();
  int r0 = kc*256;
  for (int i = t; i < BNUM*256; i += 64){
    int b = i>>8, dl = i&255;
    xs[b][dl] = h[b*DNUM + r0 + dl] * invs[b] * nw[r0 + dl];
  }
  __syncthreads();
  int p0 = pb*256 + t*4;
  if (p0 >= PNUM) return;
  float4 acc[BNUM];
  #pragma unroll
  for (int b = 0; b < BNUM; ++b) acc[b] = make_float4(0.f,0.f,0.f,0.f);
  const float* wp = W + (size_t)r0*PNUM + p0;
  #pragma unroll 8
  for (int dl = 0; dl < 256; ++dl){
    float4 w4 = *(const float4*)wp;
    wp += PNUM;
    #pragma unroll
    for (int b = 0; b < BNUM; ++b){
      float xv = xs[b][dl];
      acc[b].x += xv*w4.x; acc[b].y += xv*w4.y; acc[b].z += xv*w4.z; acc[b].w += xv*w4.w;
    }
  }
  #pragma unroll
  for (int b = 0; b < BNUM; ++b)
    *(float4*)(part1 + (size_t)(kc*BNUM + b)*PNUM + p0) = acc[b];
}

// ---------------- reduce partials + conv + silu + dt/dA precompute ----------------
__global__ void k_convfuse(const float* __restrict__ part1,
                           const float* __restrict__ cs_in, float* __restrict__ cs_out,
                           const float* __restrict__ cw, const float* __restrict__ cb,
                           const float* __restrict__ db, const float* __restrict__ al,
                           float* __restrict__ projg, float* __restrict__ convout,
                           float* __restrict__ dtv, float* __restrict__ dAv){
  int idx = blockIdx.x*256 + threadIdx.x;  // < B*P
  int b = idx / PNUM, p = idx - b*PNUM;
  float v = 0.f;
  #pragma unroll
  for (int kc = 0; kc < IP_KC; ++kc) v += part1[(size_t)(kc*BNUM + b)*PNUM + p];
  if (p < INUM){
    projg[b*INUM + p] = v;
  } else if (p < INUM + CONVNUM){
    int c = p - INUM;
    int sid = b*CONVNUM + c;
    float4 s = *(const float4*)(cs_in + (size_t)sid*KNUM);
    float4 ns = make_float4(s.y, s.z, s.w, v);
    *(float4*)(cs_out + (size_t)sid*KNUM) = ns;
    float4 w = *(const float4*)(cw + c*KNUM);
    float co = ns.x*w.x + ns.y*w.y + ns.z*w.z + ns.w*w.w + cb[c];
    convout[b*CONVNUM + c] = co * sigmoidf_(co);
  } else {
    int hh = p - INUM - CONVNUM;
    float dtr = v + db[hh];
    float dt = (dtr > 20.f) ? dtr : log1pf(expf(dtr));
    dt = fminf(fmaxf(dt, 0.f), 10000.f);
    float A = -expf(al[hh]);
    dtv[b*HNUM + hh] = dt;
    dAv[b*HNUM + hh] = expf(dt*A);
  }
}

// ---------------- SSM state update + gated output partials ----------------
__global__ __launch_bounds__(256) void k_ssm(const float* __restrict__ ss_in,
                                             const float* __restrict__ convout,
                                             const float* __restrict__ projg,
                                             const float* __restrict__ dtv,
                                             const float* __restrict__ dAv,
                                             const float* __restrict__ D_param,
                                             float* __restrict__ ss_out,
                                             float* __restrict__ yg,
                                             float* __restrict__ ygsq){
  int b = blockIdx.x >> 6, hh = blockIdx.x & 63;
  int t = threadIdx.x;
  __shared__ float Bs[NNUM], Cs[NNUM];
  __shared__ float sred[8];
  int g = hh >> 3;
  if (t < NNUM) Bs[t] = convout[b*CONVNUM + INUM + g*NNUM + t];
  else          Cs[t-NNUM] = convout[b*CONVNUM + INUM + GNUM*NNUM + g*NNUM + (t-NNUM)];
  __syncthreads();
  float dt = dtv[b*HNUM + hh];
  float dA = dAv[b*HNUM + hh];
  float dp = D_param[hh];
  int r = t & 31, a = t >> 5;
  float4 Bv = *(float4*)&Bs[r*4];
  float4 Cv = *(float4*)&Cs[r*4];
  const float* sin_ = ss_in  + (size_t)(b*HNUM + hh)*HDNUM*NNUM;
  float*       sout = ss_out + (size_t)(b*HNUM + hh)*HDNUM*NNUM;
  float s_yg = 0.f;
  #pragma unroll
  for (int k = 0; k < 8; ++k){
    int hd = k*8 + a;
    float xv = convout[b*CONVNUM + hh*HDNUM + hd];
    float coef = dt * xv;
    int off = k*1024 + t*4;
    float4 s4 = *(const float4*)(sin_ + off);
    float4 ns;
    ns.x = s4.x*dA + coef*Bv.x;
    ns.y = s4.y*dA + coef*Bv.y;
    ns.z = s4.z*dA + coef*Bv.z;
    ns.w = s4.w*dA + coef*Bv.w;
    *(float4*)(sout + off) = ns;
    float yp = ns.x*Cv.x + ns.y*Cv.y + ns.z*Cv.z + ns.w*Cv.w;
    yp += __shfl_xor(yp,1); yp += __shfl_xor(yp,2); yp += __shfl_xor(yp,4);
    yp += __shfl_xor(yp,8); yp += __shfl_xor(yp,16);
    if (r == 0){
      float gv = projg[b*INUM + hh*HDNUM + hd];
      float ygv = (yp + xv*dp) * gv * sigmoidf_(gv);
      yg[b*INUM + hh*HDNUM + hd] = ygv;
      s_yg += ygv*ygv;
    }
  }
  if (r == 0) sred[a] = s_yg;
  __syncthreads();
  if (t == 0){
    float tot = 0.f;
    #pragma unroll
    for (int j = 0; j < 8; ++j) tot += sred[j];
    ygsq[b*HNUM + hh] = tot;
  }
}

// ---------------- out_proj GEMV (gated rmsnorm fused via ygsq) ----------------
__global__ __launch_bounds__(64) void k_outproj(const float* __restrict__ yg,
                                                const float* __restrict__ ygsq,
                                                const float* __restrict__ gw,
                                                const float* __restrict__ W,
                                                float* __restrict__ part2){
  int t = threadIdx.x;
  int pb = blockIdx.x;   // 0..7 : 256 d-cols
  int ic = blockIdx.y;   // 0..63: 64 i-rows
  __shared__ float xs[BNUM][64];
  __shared__ float invg[BNUM];
  {
    int b = t>>3, j = t&7;
    float v = 0.f;
    #pragma unroll
    for (int jj = 0; jj < 8; ++jj) v += ygsq[b*HNUM + j + jj*8];
    v += __shfl_xor(v,1); v += __shfl_xor(v,2); v += __shfl_xor(v,4);
    if (j == 0) invg[b] = rsqrtf(v*(1.f/INUM) + 1e-5f);
  }
  __syncthreads();
  int r0 = ic*64;
  for (int i = t; i < BNUM*64; i += 64){
    int b = i>>6, il = i&63;
    xs[b][il] = yg[b*INUM + r0 + il] * invg[b] * gw[r0 + il];
  }
  __syncthreads();
  int d0 = pb*256 + t*4;
  float4 acc[BNUM];
  #pragma unroll
  for (int b = 0; b < BNUM; ++b) acc[b] = make_float4(0.f,0.f,0.f,0.f);
  const float* wp = W + (size_t)r0*DNUM + d0;
  #pragma unroll 8
  for (int il = 0; il < 64; ++il){
    float4 w4 = *(const float4*)wp;
    wp += DNUM;
    #pragma unroll
    for (int b = 0; b < BNUM; ++b){
      float xv = xs[b][il];
      acc[b].x += xv*w4.x; acc[b].y += xv*w4.y; acc[b].z += xv*w4.z; acc[b].w += xv*w4.w;
    }
  }
  #pragma unroll
  for (int b = 0; b < BNUM; ++b)
    *(float4*)(part2 + (size_t)(ic*BNUM + b)*DNUM + d0) = acc[b];
}

// ---------------- reduce out_proj partials + residual + next-layer sq partials ----------------
__global__ void k_reduce_out(const float* __restrict__ part2, float* __restrict__ h,
                             float* __restrict__ sqp){
  int idx = blockIdx.x*256 + threadIdx.x;   // < B*D
  float s = h[idx];
  #pragma unroll
  for (int ic = 0; ic < OP_KC; ++ic) s += part2[(size_t)ic*BNUM*DNUM + idx];
  h[idx] = s;
  float q = s*s;
  q += __shfl_xor(q,32); q += __shfl_xor(q,16); q += __shfl_xor(q,8);
  q += __shfl_xor(q,4);  q += __shfl_xor(q,2);  q += __shfl_xor(q,1);
  __shared__ float red[4];
  int t = threadIdx.x;
  if ((t & 63) == 0) red[t>>6] = q;
  __syncthreads();
  if (t == 0) sqp[blockIdx.x] = red[0]+red[1]+red[2]+red[3];  // blockIdx = b*8 + chunk
}

// ---------------- lm_head (final rmsnorm fused) ----------------
__global__ __launch_bounds__(256) void k_lmhead(const float* __restrict__ h,
                                                const float* __restrict__ sqp,
                                                const float* __restrict__ nf,
                                                const float* __restrict__ Wl,
                                                float* __restrict__ logits){
  __shared__ float hs[BNUM*DNUM];   // 64KB
  int t = threadIdx.x;
  float invb[8];
  #pragma unroll
  for (int b2 = 0; b2 < 8; ++b2){
    float s = 0.f;
    #pragma unroll
    for (int j = 0; j < 8; ++j) s += sqp[b2*8 + j];
    invb[b2] = rsqrtf(s*(1.f/DNUM) + 1e-5f);
  }
  #pragma unroll
  for (int it = 0; it < 16; ++it){
    int i = t*4 + it*1024;
    float iv = invb[it>>1];
    float4 hv  = *(const float4*)(h + i);
    float4 nfv = *(const float4*)(nf + (i & 2047));
    float4 o;
    o.x = hv.x*iv*nfv.x; o.y = hv.y*iv*nfv.y; o.z = hv.z*iv*nfv.z; o.w = hv.w*iv*nfv.w;
    *(float4*)(hs + i) = o;
  }
  __syncthreads();
  int wv = t >> 6, lane = t & 63;
  int v0 = (blockIdx.x*4 + wv)*4;
  float acc[4][BNUM];
  #pragma unroll
  for (int u = 0; u < 4; ++u)
    #pragma unroll
    for (int b = 0; b < BNUM; ++b) acc[u][b] = 0.f;
  #pragma unroll
  for (int j = 0; j < 8; ++j){
    int dbase = j*256 + lane*4;
    float4 w0 = *(const float4*)(Wl + (size_t)(v0+0)*DNUM + dbase);
    float4 w1 = *(const float4*)(Wl + (size_t)(v0+1)*DNUM + dbase);
    float4 w2 = *(const float4*)(Wl + (size_t)(v0+2)*DNUM + dbase);
    float4 w3 = *(const float4*)(Wl + (size_t)(v0+3)*DNUM + dbase);
    #pragma unroll
    for (int b = 0; b < BNUM; ++b){
      float4 hv = *(const float4*)(hs + b*DNUM + dbase);
      acc[0][b] += w0.x*hv.x + w0.y*hv.y + w0.z*hv.z + w0.w*hv.w;
      acc[1][b] += w1.x*hv.x + w1.y*hv.y + w1.z*hv.z + w1.w*hv.w;
      acc[2][b] += w2.x*hv.x + w2.y*hv.y + w2.z*hv.z + w2.w*hv.w;
      acc[3][b] += w3.x*hv.x + w3.y*hv.y + w3.z*hv.z + w3.w*hv.w;
    }
  }
  #pragma unroll
  for (int u = 0; u < 4; ++u)
    #pragma unroll
    for (int b = 0; b < BNUM; ++b){
      float s = acc[u][b];
      s += __shfl_xor(s,32); s += __shfl_xor(s,16); s += __shfl_xor(s,8);
      s += __shfl_xor(s,4);  s += __shfl_xor(s,2);  s += __shfl_xor(s,1);
      if (lane == 0) logits[(size_t)b*VNUM + v0 + u] = s;
    }
}

extern "C" void kernel_launch(void* const* d_in, const int* in_sizes, int n_in,
                              void* d_out, int out_size, void* d_ws, size_t ws_size,
                              hipStream_t stream){
  const int*   ids         = (const int*)d_in[0];
  const float* conv_states = (const float*)d_in[1];
  const float* ssm_states  = (const float*)d_in[2];
  const float* emb         = (const float*)d_in[3];
  const float* norm_w      = (const float*)d_in[4];
  const float* in_proj_w   = (const float*)d_in[5];
  const float* conv_w      = (const float*)d_in[6];
  const float* conv_b      = (const float*)d_in[7];
  const float* dt_bias     = (const float*)d_in[8];
  const float* A_log       = (const float*)d_in[9];
  const float* D_param     = (const float*)d_in[10];
  const float* gn_w        = (const float*)d_in[11];
  const float* out_proj_w  = (const float*)d_in[12];
  const float* norm_f_w    = (const float*)d_in[13];
  const float* lm_head_w   = (const float*)d_in[14];

  float* out         = (float*)d_out;
  float* logits      = out;
  float* conv_out_st = out + (size_t)BNUM*VNUM;
  float* ssm_out_st  = conv_out_st + (size_t)LNUM*BNUM*CONVNUM*KNUM;

  float* ws      = (float*)d_ws;
  float* h       = ws;                    // B*D            = 16384
  float* projg   = h      + 16384;        // B*I            = 32768
  float* convout = projg  + 32768;        // B*CONV         = 49152
  float* dtv     = convout+ 49152;        // B*H            = 512
  float* dAv     = dtv    + 512;          // B*H            = 512
  float* yg      = dAv    + 512;          // B*I            = 32768
  float* ygsq    = yg     + 32768;        // B*H            = 512
  float* sqp     = ygsq   + 512;          // B*8            = 64
  float* part1   = sqp    + 64;           // 8*B*P          = 915456
  float* part2   = part1  + 915456;       // 64*B*D         = 1048576

  k_embed<<<BNUM, 256, 0, stream>>>(ids, emb, h, sqp);

  for (int l = 0; l < LNUM; ++l){
    dim3 g1(56, IP_KC);
    k_inproj<<<g1, 64, 0, stream>>>(h, sqp, norm_w + (size_t)l*DNUM,
                                    in_proj_w + (size_t)l*DNUM*PNUM, part1);
    k_convfuse<<<(BNUM*PNUM)/256, 256, 0, stream>>>(
        part1,
        conv_states + (size_t)l*BNUM*CONVNUM*KNUM,
        conv_out_st + (size_t)l*BNUM*CONVNUM*KNUM,
        conv_w + (size_t)l*CONVNUM*KNUM, conv_b + (size_t)l*CONVNUM,
        dt_bias + (size_t)l*HNUM, A_log + (size_t)l*HNUM,
        projg, convout, dtv, dAv);
    k_ssm<<<BNUM*HNUM, 256, 0, stream>>>(
        ssm_states + (size_t)l*BNUM*HNUM*HDNUM*NNUM, convout, projg, dtv, dAv,
        D_param + (size_t)l*HNUM,
        ssm_out_st + (size_t)l*BNUM*HNUM*HDNUM*NNUM, yg, ygsq);
    dim3 g2(8, OP_KC);
    k_outproj<<<g2, 64, 0, stream>>>(yg, ygsq, gn_w + (size_t)l*INUM,
                                     out_proj_w + (size_t)l*INUM*DNUM, part2);
    k_reduce_out<<<64, 256, 0, stream>>>(part2, h, sqp);
  }

  k_lmhead<<<VNUM/16, 256, 0, stream>>>(h, sqp, norm_f_w, lm_head_w, logits);
}

// Round 3
// 946.129 us; speedup vs baseline: 1.9607x; 1.9607x over previous
//
#include <hip/hip_runtime.h>
#include <hip/hip_bf16.h>
#include <math.h>

#define LNUM 12
#define BNUM 8
#define DNUM 2048
#define VNUM 32000
#define HNUM 64
#define HDNUM 64
#define GNUM 8
#define NNUM 128
#define KNUM 4
#define INUM (HNUM*HDNUM)              /* 4096 */
#define CONVNUM (INUM + 2*GNUM*NNUM)   /* 6144 */
#define PNUM (INUM + CONVNUM + HNUM)   /* 14304 */

#define IP_KC 16                       /* in_proj row chunks (128 rows, 4 waves x 32) */
#define OP_KC 64                       /* out_proj row chunks (64 rows, 4 waves x 16) */

__device__ __forceinline__ float sigmoidf_(float x){ return 1.f/(1.f+expf(-x)); }

// ---------------- embedding gather + sumsq partials ----------------
__global__ void k_embed(const int* __restrict__ ids, const float* __restrict__ emb,
                        float* __restrict__ h, float* __restrict__ sqp){
  int b = blockIdx.x; int t = threadIdx.x;
  const float* src = emb + (size_t)ids[b]*DNUM;
  float* dst = h + (size_t)b*DNUM;
  for (int d = t*4; d < DNUM; d += 256*4)
    *(float4*)(dst + d) = *(const float4*)(src + d);
  __shared__ float red[4];
  for (int j = 0; j < 8; ++j){
    float v = src[j*256 + t];
    float q = v*v;
    q += __shfl_xor(q,32); q += __shfl_xor(q,16); q += __shfl_xor(q,8);
    q += __shfl_xor(q,4);  q += __shfl_xor(q,2);  q += __shfl_xor(q,1);
    if ((t & 63) == 0) red[t>>6] = q;
    __syncthreads();
    if (t == 0) sqp[b*8 + j] = red[0]+red[1]+red[2]+red[3];
    __syncthreads();
  }
}

// ---------------- in_proj GEMV (rmsnorm fused), intra-block K-split ----------------
// grid (56, 16), block 256. Block (pb,kc): cols [pb*256,+256), rows [kc*128,+128).
// Wave w handles rows [kc*128 + w*32, +32). LDS-reduce across waves, one partial/chunk.
__global__ __launch_bounds__(256) void k_inproj(const float* __restrict__ h,
                                                const float* __restrict__ sqp,
                                                const float* __restrict__ nw,
                                                const float* __restrict__ W,
                                                float* __restrict__ part1){
  int t = threadIdx.x, w = t >> 6, l = t & 63;
  int pb = blockIdx.x, kc = blockIdx.y;
  __shared__ float xs[BNUM][128];
  __shared__ float invs[BNUM];
  __shared__ float4 red[4][BNUM][64];   // 32 KB
  if (t < 64){
    int b = t>>3, j = t&7;
    float v = sqp[b*8 + j];
    v += __shfl_xor(v,1); v += __shfl_xor(v,2); v += __shfl_xor(v,4);
    if (j == 0) invs[b] = rsqrtf(v*(1.f/DNUM) + 1e-5f);
  }
  __syncthreads();
  int r0 = kc*128;
  for (int i = t; i < BNUM*128; i += 256){
    int b = i>>7, dl = i&127;
    xs[b][dl] = h[b*DNUM + r0 + dl] * invs[b] * nw[r0 + dl];
  }
  __syncthreads();
  int p0 = pb*256 + l*4;
  bool valid = (p0 < PNUM);
  float4 acc[BNUM];
  #pragma unroll
  for (int b = 0; b < BNUM; ++b) acc[b] = make_float4(0.f,0.f,0.f,0.f);
  if (valid){
    int rbase = w*32;
    const float* wp = W + (size_t)(r0 + rbase)*PNUM + p0;
    #pragma unroll 4
    for (int r = 0; r < 32; ++r){
      float4 w4 = *(const float4*)wp;
      wp += PNUM;
      #pragma unroll
      for (int b = 0; b < BNUM; ++b){
        float xv = xs[b][rbase + r];
        acc[b].x += xv*w4.x; acc[b].y += xv*w4.y; acc[b].z += xv*w4.z; acc[b].w += xv*w4.w;
      }
    }
  }
  #pragma unroll
  for (int b = 0; b < BNUM; ++b) red[w][b][l] = acc[b];
  __syncthreads();
  if (w == 0 && valid){
    #pragma unroll
    for (int b = 0; b < BNUM; ++b){
      float4 s0 = red[0][b][l], s1 = red[1][b][l], s2 = red[2][b][l], s3 = red[3][b][l];
      float4 s;
      s.x = (s0.x+s1.x)+(s2.x+s3.x);
      s.y = (s0.y+s1.y)+(s2.y+s3.y);
      s.z = (s0.z+s1.z)+(s2.z+s3.z);
      s.w = (s0.w+s1.w)+(s2.w+s3.w);
      *(float4*)(part1 + (size_t)(kc*BNUM + b)*PNUM + p0) = s;
    }
  }
}

// ---------------- reduce partials + conv + silu + dt/dA precompute ----------------
__global__ void k_convfuse(const float* __restrict__ part1,
                           const float* __restrict__ cs_in, float* __restrict__ cs_out,
                           const float* __restrict__ cw, const float* __restrict__ cb,
                           const float* __restrict__ db, const float* __restrict__ al,
                           float* __restrict__ projg, float* __restrict__ convout,
                           float* __restrict__ dtv, float* __restrict__ dAv){
  int idx = blockIdx.x*256 + threadIdx.x;  // < B*P
  int b = idx / PNUM, p = idx - b*PNUM;
  float v = 0.f;
  #pragma unroll
  for (int kc = 0; kc < IP_KC; ++kc) v += part1[(size_t)(kc*BNUM + b)*PNUM + p];
  if (p < INUM){
    projg[b*INUM + p] = v;
  } else if (p < INUM + CONVNUM){
    int c = p - INUM;
    int sid = b*CONVNUM + c;
    float4 s = *(const float4*)(cs_in + (size_t)sid*KNUM);
    float4 ns = make_float4(s.y, s.z, s.w, v);
    *(float4*)(cs_out + (size_t)sid*KNUM) = ns;
    float4 w = *(const float4*)(cw + c*KNUM);
    float co = ns.x*w.x + ns.y*w.y + ns.z*w.z + ns.w*w.w + cb[c];
    convout[b*CONVNUM + c] = co * sigmoidf_(co);
  } else {
    int hh = p - INUM - CONVNUM;
    float dtr = v + db[hh];
    float dt = (dtr > 20.f) ? dtr : log1pf(expf(dtr));
    dt = fminf(fmaxf(dt, 0.f), 10000.f);
    float A = -expf(al[hh]);
    dtv[b*HNUM + hh] = dt;
    dAv[b*HNUM + hh] = expf(dt*A);
  }
}

// ---------------- SSM state update + gated output partials ----------------
__global__ __launch_bounds__(256) void k_ssm(const float* __restrict__ ss_in,
                                             const float* __restrict__ convout,
                                             const float* __restrict__ projg,
                                             const float* __restrict__ dtv,
                                             const float* __restrict__ dAv,
                                             const float* __restrict__ D_param,
                                             float* __restrict__ ss_out,
                                             float* __restrict__ yg,
                                             float* __restrict__ ygsq){
  int b = blockIdx.x >> 6, hh = blockIdx.x & 63;
  int t = threadIdx.x;
  __shared__ float Bs[NNUM], Cs[NNUM];
  __shared__ float sred[8];
  int g = hh >> 3;
  if (t < NNUM) Bs[t] = convout[b*CONVNUM + INUM + g*NNUM + t];
  else          Cs[t-NNUM] = convout[b*CONVNUM + INUM + GNUM*NNUM + g*NNUM + (t-NNUM)];
  __syncthreads();
  float dt = dtv[b*HNUM + hh];
  float dA = dAv[b*HNUM + hh];
  float dp = D_param[hh];
  int r = t & 31, a = t >> 5;
  float4 Bv = *(float4*)&Bs[r*4];
  float4 Cv = *(float4*)&Cs[r*4];
  const float* sin_ = ss_in  + (size_t)(b*HNUM + hh)*HDNUM*NNUM;
  float*       sout = ss_out + (size_t)(b*HNUM + hh)*HDNUM*NNUM;
  float s_yg = 0.f;
  #pragma unroll
  for (int k = 0; k < 8; ++k){
    int hd = k*8 + a;
    float xv = convout[b*CONVNUM + hh*HDNUM + hd];
    float coef = dt * xv;
    int off = k*1024 + t*4;
    float4 s4 = *(const float4*)(sin_ + off);
    float4 ns;
    ns.x = s4.x*dA + coef*Bv.x;
    ns.y = s4.y*dA + coef*Bv.y;
    ns.z = s4.z*dA + coef*Bv.z;
    ns.w = s4.w*dA + coef*Bv.w;
    *(float4*)(sout + off) = ns;
    float yp = ns.x*Cv.x + ns.y*Cv.y + ns.z*Cv.z + ns.w*Cv.w;
    yp += __shfl_xor(yp,1); yp += __shfl_xor(yp,2); yp += __shfl_xor(yp,4);
    yp += __shfl_xor(yp,8); yp += __shfl_xor(yp,16);
    if (r == 0){
      float gv = projg[b*INUM + hh*HDNUM + hd];
      float ygv = (yp + xv*dp) * gv * sigmoidf_(gv);
      yg[b*INUM + hh*HDNUM + hd] = ygv;
      s_yg += ygv*ygv;
    }
  }
  if (r == 0) sred[a] = s_yg;
  __syncthreads();
  if (t == 0){
    float tot = 0.f;
    #pragma unroll
    for (int j = 0; j < 8; ++j) tot += sred[j];
    ygsq[b*HNUM + hh] = tot;
  }
}

// ---------------- out_proj GEMV (gated rmsnorm fused), intra-block K-split ----------------
// grid (8, 64), block 256. Block (pb,kc): cols [pb*256,+256), rows [kc*64,+64).
// Wave w handles rows [kc*64 + w*16, +16).
__global__ __launch_bounds__(256) void k_outproj(const float* __restrict__ yg,
                                                 const float* __restrict__ ygsq,
                                                 const float* __restrict__ gw,
                                                 const float* __restrict__ W,
                                                 float* __restrict__ part2){
  int t = threadIdx.x, w = t >> 6, l = t & 63;
  int pb = blockIdx.x, kc = blockIdx.y;
  __shared__ float xs[BNUM][64];
  __shared__ float invg[BNUM];
  __shared__ float4 red[4][BNUM][64];   // 32 KB
  if (t < 64){
    int b = t>>3, j = t&7;
    float v = 0.f;
    #pragma unroll
    for (int jj = 0; jj < 8; ++jj) v += ygsq[b*HNUM + j + jj*8];
    v += __shfl_xor(v,1); v += __shfl_xor(v,2); v += __shfl_xor(v,4);
    if (j == 0) invg[b] = rsqrtf(v*(1.f/INUM) + 1e-5f);
  }
  __syncthreads();
  int r0 = kc*64;
  for (int i = t; i < BNUM*64; i += 256){
    int b = i>>6, il = i&63;
    xs[b][il] = yg[b*INUM + r0 + il] * invg[b] * gw[r0 + il];
  }
  __syncthreads();
  int d0 = pb*256 + l*4;
  float4 acc[BNUM];
  #pragma unroll
  for (int b = 0; b < BNUM; ++b) acc[b] = make_float4(0.f,0.f,0.f,0.f);
  {
    int rbase = w*16;
    const float* wp = W + (size_t)(r0 + rbase)*DNUM + d0;
    #pragma unroll 4
    for (int r = 0; r < 16; ++r){
      float4 w4 = *(const float4*)wp;
      wp += DNUM;
      #pragma unroll
      for (int b = 0; b < BNUM; ++b){
        float xv = xs[b][rbase + r];
        acc[b].x += xv*w4.x; acc[b].y += xv*w4.y; acc[b].z += xv*w4.z; acc[b].w += xv*w4.w;
      }
    }
  }
  #pragma unroll
  for (int b = 0; b < BNUM; ++b) red[w][b][l] = acc[b];
  __syncthreads();
  if (w == 0){
    #pragma unroll
    for (int b = 0; b < BNUM; ++b){
      float4 s0 = red[0][b][l], s1 = red[1][b][l], s2 = red[2][b][l], s3 = red[3][b][l];
      float4 s;
      s.x = (s0.x+s1.x)+(s2.x+s3.x);
      s.y = (s0.y+s1.y)+(s2.y+s3.y);
      s.z = (s0.z+s1.z)+(s2.z+s3.z);
      s.w = (s0.w+s1.w)+(s2.w+s3.w);
      *(float4*)(part2 + (size_t)(kc*BNUM + b)*DNUM + d0) = s;
    }
  }
}

// ---------------- reduce out_proj partials + residual + next-layer sq partials ----------------
__global__ void k_reduce_out(const float* __restrict__ part2, float* __restrict__ h,
                             float* __restrict__ sqp){
  int idx = blockIdx.x*256 + threadIdx.x;   // < B*D
  float s = h[idx];
  #pragma unroll
  for (int ic = 0; ic < OP_KC; ++ic) s += part2[(size_t)ic*BNUM*DNUM + idx];
  h[idx] = s;
  float q = s*s;
  q += __shfl_xor(q,32); q += __shfl_xor(q,16); q += __shfl_xor(q,8);
  q += __shfl_xor(q,4);  q += __shfl_xor(q,2);  q += __shfl_xor(q,1);
  __shared__ float red[4];
  int t = threadIdx.x;
  if ((t & 63) == 0) red[t>>6] = q;
  __syncthreads();
  if (t == 0) sqp[blockIdx.x] = red[0]+red[1]+red[2]+red[3];  // blockIdx = b*8 + chunk
}

// ---------------- lm_head (final rmsnorm fused) ----------------
__global__ __launch_bounds__(256) void k_lmhead(const float* __restrict__ h,
                                                const float* __restrict__ sqp,
                                                const float* __restrict__ nf,
                                                const float* __restrict__ Wl,
                                                float* __restrict__ logits){
  __shared__ float hs[BNUM*DNUM];   // 64KB
  int t = threadIdx.x;
  float invb[8];
  #pragma unroll
  for (int b2 = 0; b2 < 8; ++b2){
    float s = 0.f;
    #pragma unroll
    for (int j = 0; j < 8; ++j) s += sqp[b2*8 + j];
    invb[b2] = rsqrtf(s*(1.f/DNUM) + 1e-5f);
  }
  #pragma unroll
  for (int it = 0; it < 16; ++it){
    int i = t*4 + it*1024;
    float iv = invb[it>>1];
    float4 hv  = *(const float4*)(h + i);
    float4 nfv = *(const float4*)(nf + (i & 2047));
    float4 o;
    o.x = hv.x*iv*nfv.x; o.y = hv.y*iv*nfv.y; o.z = hv.z*iv*nfv.z; o.w = hv.w*iv*nfv.w;
    *(float4*)(hs + i) = o;
  }
  __syncthreads();
  int wv = t >> 6, lane = t & 63;
  int v0 = (blockIdx.x*4 + wv)*4;
  float acc[4][BNUM];
  #pragma unroll
  for (int u = 0; u < 4; ++u)
    #pragma unroll
    for (int b = 0; b < BNUM; ++b) acc[u][b] = 0.f;
  #pragma unroll
  for (int j = 0; j < 8; ++j){
    int dbase = j*256 + lane*4;
    float4 w0 = *(const float4*)(Wl + (size_t)(v0+0)*DNUM + dbase);
    float4 w1 = *(const float4*)(Wl + (size_t)(v0+1)*DNUM + dbase);
    float4 w2 = *(const float4*)(Wl + (size_t)(v0+2)*DNUM + dbase);
    float4 w3 = *(const float4*)(Wl + (size_t)(v0+3)*DNUM + dbase);
    #pragma unroll
    for (int b = 0; b < BNUM; ++b){
      float4 hv = *(const float4*)(hs + b*DNUM + dbase);
      acc[0][b] += w0.x*hv.x + w0.y*hv.y + w0.z*hv.z + w0.w*hv.w;
      acc[1][b] += w1.x*hv.x + w1.y*hv.y + w1.z*hv.z + w1.w*hv.w;
      acc[2][b] += w2.x*hv.x + w2.y*hv.y + w2.z*hv.z + w2.w*hv.w;
      acc[3][b] += w3.x*hv.x + w3.y*hv.y + w3.z*hv.z + w3.w*hv.w;
    }
  }
  #pragma unroll
  for (int u = 0; u < 4; ++u)
    #pragma unroll
    for (int b = 0; b < BNUM; ++b){
      float s = acc[u][b];
      s += __shfl_xor(s,32); s += __shfl_xor(s,16); s += __shfl_xor(s,8);
      s += __shfl_xor(s,4);  s += __shfl_xor(s,2);  s += __shfl_xor(s,1);
      if (lane == 0) logits[(size_t)b*VNUM + v0 + u] = s;
    }
}

extern "C" void kernel_launch(void* const* d_in, const int* in_sizes, int n_in,
                              void* d_out, int out_size, void* d_ws, size_t ws_size,
                              hipStream_t stream){
  const int*   ids         = (const int*)d_in[0];
  const float* conv_states = (const float*)d_in[1];
  const float* ssm_states  = (const float*)d_in[2];
  const float* emb         = (const float*)d_in[3];
  const float* norm_w      = (const float*)d_in[4];
  const float* in_proj_w   = (const float*)d_in[5];
  const float* conv_w      = (const float*)d_in[6];
  const float* conv_b      = (const float*)d_in[7];
  const float* dt_bias     = (const float*)d_in[8];
  const float* A_log       = (const float*)d_in[9];
  const float* D_param     = (const float*)d_in[10];
  const float* gn_w        = (const float*)d_in[11];
  const float* out_proj_w  = (const float*)d_in[12];
  const float* norm_f_w    = (const float*)d_in[13];
  const float* lm_head_w   = (const float*)d_in[14];

  float* out         = (float*)d_out;
  float* logits      = out;
  float* conv_out_st = out + (size_t)BNUM*VNUM;
  float* ssm_out_st  = conv_out_st + (size_t)LNUM*BNUM*CONVNUM*KNUM;

  float* ws      = (float*)d_ws;
  float* h       = ws;                    // B*D            = 16384
  float* projg   = h      + 16384;        // B*I            = 32768
  float* convout = projg  + 32768;        // B*CONV         = 49152
  float* dtv     = convout+ 49152;        // B*H            = 512
  float* dAv     = dtv    + 512;          // B*H            = 512
  float* yg      = dAv    + 512;          // B*I            = 32768
  float* ygsq    = yg     + 32768;        // B*H            = 512
  float* sqp     = ygsq   + 512;          // B*8            = 64
  float* part1   = sqp    + 64;           // 16*B*P         = 1830912
  float* part2   = part1  + 1830912;      // 64*B*D         = 1048576

  k_embed<<<BNUM, 256, 0, stream>>>(ids, emb, h, sqp);

  for (int l = 0; l < LNUM; ++l){
    dim3 g1(56, IP_KC);
    k_inproj<<<g1, 256, 0, stream>>>(h, sqp, norm_w + (size_t)l*DNUM,
                                     in_proj_w + (size_t)l*DNUM*PNUM, part1);
    k_convfuse<<<(BNUM*PNUM)/256, 256, 0, stream>>>(
        part1,
        conv_states + (size_t)l*BNUM*CONVNUM*KNUM,
        conv_out_st + (size_t)l*BNUM*CONVNUM*KNUM,
        conv_w + (size_t)l*CONVNUM*KNUM, conv_b + (size_t)l*CONVNUM,
        dt_bias + (size_t)l*HNUM, A_log + (size_t)l*HNUM,
        projg, convout, dtv, dAv);
    k_ssm<<<BNUM*HNUM, 256, 0, stream>>>(
        ssm_states + (size_t)l*BNUM*HNUM*HDNUM*NNUM, convout, projg, dtv, dAv,
        D_param + (size_t)l*HNUM,
        ssm_out_st + (size_t)l*BNUM*HNUM*HDNUM*NNUM, yg, ygsq);
    dim3 g2(8, OP_KC);
    k_outproj<<<g2, 256, 0, stream>>>(yg, ygsq, gn_w + (size_t)l*INUM,
                                      out_proj_w + (size_t)l*INUM*DNUM, part2);
    k_reduce_out<<<64, 256, 0, stream>>>(part2, h, sqp);
  }

  k_lmhead<<<VNUM/16, 256, 0, stream>>>(h, sqp, norm_f_w, lm_head_w, logits);
}